// Round 3
// baseline (58.510 us; speedup 1.0000x reference)
//
#include <hip/hip_runtime.h>
#include <hip/hip_bf16.h>

// BarlowTwins loss: logits[b,n,m] = sum_s z1[b,s,n]*z2[b,s,m]  (B=8, S=256, N=M=2048)
// loss = mean_{b,m}( LSE_n(logits[b,:,m]) - logits[b,m,m] )
//
// Round-3 structure:
//  K1 (prepass): f32 [b][s][n] -> bf16 [b][n][s] (K-major) for both inputs; z2 scaled
//     by log2e. LDS-tiled 64x64 transpose, stride-65 padding (conflict-free).
//  K2 (gemm+LSE): NO LDS, NO packing. 256 blocks (b = bid&7 -> per-XCD 2MB L2 set),
//     8 waves: wave (wm,wn) owns 64 m-cols (2 strips, B in 128 VGPR) x 256 n.
//     A-frags: direct dwordx4 loads, L1-resident (32 rows x 512B = 16KB per subtile;
//     per-t barrier keeps wm-waves in phase for L1 sharing). acc init -96, exp2-sum
//     without max tracking (headroom analysis: col max' ~90 << 128+96).
//  K3/K4: merge partials -> log2(sum)-diag -> mean.

#define NN 2048
#define SK 256
#define LOG2E 1.4426950408889634f
#define LN2   0.6931471805599453f
#define COFF  96.0f

typedef __attribute__((ext_vector_type(8))) short short8;
typedef __attribute__((ext_vector_type(16))) float f32x16;

__device__ __forceinline__ unsigned short f2bf(float f) {
    __hip_bfloat16 h = __float2bfloat16(f);
    unsigned short u; __builtin_memcpy(&u, &h, 2); return u;
}

__device__ __forceinline__ float exp2g(float x) {
#if __has_builtin(__builtin_amdgcn_exp2f)
    return __builtin_amdgcn_exp2f(x);
#else
    return exp2f(x);
#endif
}

__device__ __forceinline__ float log2g(float x) {
#if __has_builtin(__builtin_amdgcn_logf)
    return __builtin_amdgcn_logf(x);
#else
    return log2f(x);
#endif
}

// ---------------- K1: transpose + cvt prepass ----------------
__global__ __launch_bounds__(256) void transpose_kernel(
    const float* __restrict__ z1, const float* __restrict__ z2,
    unsigned short* __restrict__ z1t, unsigned short* __restrict__ z2t)
{
    __shared__ float lds[64][65];   // stride 65: phase1 & phase2 both <=2-way (free)

    const int bid  = blockIdx.x;        // 2048 blocks
    const int arr  = bid >> 10;         // 0: z1, 1: z2
    const int rest = bid & 1023;
    const int b    = rest >> 7;
    const int st   = (rest >> 5) & 3;   // s-tile (4 x 64)
    const int nt   = rest & 31;         // n-tile (32 x 64)

    const float* in = (arr ? z2 : z1) + (size_t)b * SK * NN + (size_t)(st * 64) * NN + nt * 64;
    unsigned short* out = (arr ? z2t : z1t) + (size_t)b * NN * SK + (size_t)(nt * 64) * SK + st * 64;
    const float scale = arr ? LOG2E : 1.0f;

    const int tid = threadIdx.x;
    const int n4 = tid & 15, sl = tid >> 4;   // sl 0..15
    #pragma unroll
    for (int r = 0; r < 4; ++r) {
        const int s = r * 16 + sl;
        float4 v = *(const float4*)(in + (size_t)s * NN + n4 * 4);
        lds[n4 * 4 + 0][s] = v.x * scale;
        lds[n4 * 4 + 1][s] = v.y * scale;
        lds[n4 * 4 + 2][s] = v.z * scale;
        lds[n4 * 4 + 3][s] = v.w * scale;
    }
    __syncthreads();

    const int nr = tid >> 2, q = tid & 3;
    short8 o0, o1;
    #pragma unroll
    for (int i = 0; i < 8; ++i) o0[i] = (short)f2bf(lds[nr][q * 16 + i]);
    #pragma unroll
    for (int i = 0; i < 8; ++i) o1[i] = (short)f2bf(lds[nr][q * 16 + 8 + i]);
    *(short8*)(out + (size_t)nr * SK + q * 16)     = o0;
    *(short8*)(out + (size_t)nr * SK + q * 16 + 8) = o1;
}

// ---------------- K2: LDS-free fused GEMM + exp2-sum ----------------
__global__ __launch_bounds__(512, 2) void gemm_lse_kernel(
    const unsigned short* __restrict__ z1t, const unsigned short* __restrict__ z2t,
    float* __restrict__ ws_sum, float* __restrict__ ws_diag)
{
    const int bid  = blockIdx.x;
    const int b    = bid & 7;          // XCD-aligned batch
    const int tile = bid >> 3;
    const int mb   = tile & 7;         // 8 m-blocks of 256
    const int ns   = tile >> 3;        // 4 n-splits of 512
    const int tid  = threadIdx.x;
    const int lane = tid & 63;
    const int w    = tid >> 6;
    const int wm   = w >> 1;           // 0..3
    const int wn   = w & 1;            // 0..1
    const int col  = lane & 31;
    const int kg   = lane >> 5;

    const int m0 = mb * 256 + wm * 64;        // strip0; strip1 = +32
    const int n0 = ns * 512 + wn * 256;       // this wave's 256 n

    const unsigned short* z1b = z1t + (size_t)b * NN * SK;
    const unsigned short* z2b = z2t + (size_t)b * NN * SK;

    // B fragments: 2 strips x K=256 in registers (32 dwordx4 loads)
    short8 bf0[16], bf1[16];
    {
        const unsigned short* b0p = z2b + (size_t)(m0 + col) * SK + kg * 8;
        const unsigned short* b1p = b0p + 32 * SK;
        #pragma unroll
        for (int ks = 0; ks < 16; ++ks) {
            bf0[ks] = *(const short8*)(b0p + ks * 16);
            bf1[ks] = *(const short8*)(b1p + ks * 16);
        }
    }

    const unsigned short* ap = z1b + (size_t)(n0 + col) * SK + kg * 8;
    float srun0 = 0.0f, srun1 = 0.0f;

    for (int t = 0; t < 8; ++t) {
        const unsigned short* ab = ap + (size_t)t * 32 * SK;

        f32x16 acc0, acc1;
        #pragma unroll
        for (int r = 0; r < 16; ++r) { acc0[r] = -COFF; acc1[r] = -COFF; }

        // 4-deep rolling A-frag prefetch
        short8 af0 = *(const short8*)(ab);
        short8 af1 = *(const short8*)(ab + 16);
        short8 af2 = *(const short8*)(ab + 32);
        short8 af3 = *(const short8*)(ab + 48);
        #pragma unroll
        for (int ks = 0; ks < 16; ++ks) {
            short8 cur;
            if ((ks & 3) == 0) cur = af0;
            else if ((ks & 3) == 1) cur = af1;
            else if ((ks & 3) == 2) cur = af2;
            else cur = af3;
            if (ks < 12) {
                short8 nxt = *(const short8*)(ab + (ks + 4) * 16);
                if ((ks & 3) == 0) af0 = nxt;
                else if ((ks & 3) == 1) af1 = nxt;
                else if ((ks & 3) == 2) af2 = nxt;
                else af3 = nxt;
            }
            acc0 = __builtin_amdgcn_mfma_f32_32x32x16_bf16(cur, bf0[ks], acc0, 0, 0, 0);
            acc1 = __builtin_amdgcn_mfma_f32_32x32x16_bf16(cur, bf1[ks], acc1, 0, 0, 0);
        }

        // diagonal capture (acc = logit' - 96; offset cancels in merge)
        const int nsub = n0 + 32 * t;
        if (nsub == m0) {
            #pragma unroll
            for (int r = 0; r < 16; ++r) {
                const int row = (r & 3) + 8 * (r >> 2) + 4 * kg;
                if (row == col) ws_diag[b * NN + m0 + col] = acc0[r];
            }
        }
        if (nsub == m0 + 32) {
            #pragma unroll
            for (int r = 0; r < 16; ++r) {
                const int row = (r & 3) + 8 * (r >> 2) + 4 * kg;
                if (row == col) ws_diag[b * NN + m0 + 32 + col] = acc1[r];
            }
        }

        // exp2-sum, 4 independent chains per strip
        {
            float e0 = 0, e1 = 0, e2 = 0, e3 = 0;
            #pragma unroll
            for (int r = 0; r < 16; r += 4) {
                e0 += exp2g(acc0[r]);     e1 += exp2g(acc0[r + 1]);
                e2 += exp2g(acc0[r + 2]); e3 += exp2g(acc0[r + 3]);
            }
            srun0 += (e0 + e1) + (e2 + e3);
        }
        {
            float e0 = 0, e1 = 0, e2 = 0, e3 = 0;
            #pragma unroll
            for (int r = 0; r < 16; r += 4) {
                e0 += exp2g(acc1[r]);     e1 += exp2g(acc1[r + 1]);
                e2 += exp2g(acc1[r + 2]); e3 += exp2g(acc1[r + 3]);
            }
            srun1 += (e0 + e1) + (e2 + e3);
        }

        __syncthreads();   // no LDS: pure wave-phase sync to keep L1 A-set shared
    }

    srun0 += __shfl_xor(srun0, 32);
    srun1 += __shfl_xor(srun1, 32);
    if (kg == 0) {
        const int slot = ns * 2 + wn;   // 8 n-partials per (b,m)
        ws_sum[(b * 8 + slot) * NN + m0 + col]      = srun0;
        ws_sum[(b * 8 + slot) * NN + m0 + 32 + col] = srun1;
    }
}

// ---------------- K3/K4: merge + reduce ----------------
__global__ __launch_bounds__(256) void merge_kernel(
    const float* __restrict__ ws_sum, const float* __restrict__ ws_diag,
    float* __restrict__ partial)
{
    const int gid = blockIdx.x * 256 + threadIdx.x;   // 0..16383
    const int b = gid >> 11, m = gid & (NN - 1);

    float S = 0.0f;
    #pragma unroll
    for (int slot = 0; slot < 8; ++slot)
        S += ws_sum[(b * 8 + slot) * NN + m];
    float c = log2g(S) - ws_diag[gid];   // (LSE' - diag') in log2 units

    #pragma unroll
    for (int d = 1; d < 64; d <<= 1) c += __shfl_xor(c, d);
    __shared__ float red[4];
    if ((threadIdx.x & 63) == 0) red[threadIdx.x >> 6] = c;
    __syncthreads();
    if (threadIdx.x == 0)
        partial[blockIdx.x] = red[0] + red[1] + red[2] + red[3];
}

__global__ void final_kernel(const float* __restrict__ partial, float* __restrict__ out)
{
    float v = partial[threadIdx.x];   // 64 threads
    #pragma unroll
    for (int d = 1; d < 64; d <<= 1) v += __shfl_xor(v, d);
    if (threadIdx.x == 0) out[0] = v * (LN2 / 16384.0f);
}

extern "C" void kernel_launch(void* const* d_in, const int* in_sizes, int n_in,
                              void* d_out, int out_size, void* d_ws, size_t ws_size,
                              hipStream_t stream)
{
    const float* z1 = (const float*)d_in[0];
    const float* z2 = (const float*)d_in[1];
    float* out = (float*)d_out;

    // ws layout: z1t bf16 [8][2048][256] (8MB) | z2t (8MB) | sum f32 [8][8][2048] | diag [8][2048] | partial[64]
    char* wsb = (char*)d_ws;
    unsigned short* z1t = (unsigned short*)wsb;
    unsigned short* z2t = (unsigned short*)(wsb + (8u << 20));
    float* ws_sum  = (float*)(wsb + (16u << 20));
    float* ws_diag = ws_sum + 8 * 8 * NN;
    float* ws_part = ws_diag + 8 * NN;

    transpose_kernel<<<dim3(2048), dim3(256), 0, stream>>>(z1, z2, z1t, z2t);
    gemm_lse_kernel<<<dim3(256), dim3(512), 0, stream>>>(z1t, z2t, ws_sum, ws_diag);
    merge_kernel<<<dim3(64), dim3(256), 0, stream>>>(ws_sum, ws_diag, ws_part);
    final_kernel<<<dim3(1), dim3(64), 0, stream>>>(ws_part, out);
}

// Round 4
// 32.198 us; speedup vs baseline: 1.8172x; 1.8172x over previous
//
#include <hip/hip_runtime.h>
#include <hip/hip_bf16.h>

// BarlowTwins loss: logits[b,n,m] = sum_s z1[b,s,n]*z2[b,s,m]  (B=8, S=256, N=M=2048)
// loss = mean_{b,m}( LSE_n(logits[b,:,m]) - logits[b,m,m] )
//
// Round-4: single fused GEMM kernel, round-2 staging machinery + double-buffered LDS.
//  - 256 blocks (1/CU), 512 thr (8 waves). b = bid&7 -> per-XCD input set = 4MB (L2-fit).
//  - Wave (wm,wn): 64 m-cols (2 strips, B-frags in 128 VGPR) x 256 n (8 x 32-row subtiles).
//  - A staged per 64-n tile: coalesced f32 loads -> regs -> bf16 pack -> LDS (stride 264
//    ushorts: write b128 slot = lane mod 32, read slot = col -> both conflict-free; round-2
//    measured SQ_LDS_BANK_CONFLICT = 0).
//  - Double buffer, ONE barrier per tile: compute(buf[t&1]) || store_A(buf[t^1]) || load_A(t+2).
//  - No max tracking: acc init -96, exp2-sum (logits' = logit*log2e, col max' ~90 << 224).
//  - LSE - diag = ln2 * (log2(sum) - diag_acc); -96 offset cancels.

#define NN 2048
#define SK 256
#define LDST 264
#define LOG2E 1.4426950408889634f
#define LN2   0.6931471805599453f
#define COFF  96.0f

typedef __attribute__((ext_vector_type(8))) short short8;
typedef __attribute__((ext_vector_type(16))) float f32x16;

__device__ __forceinline__ unsigned short f2bf(float f) {
    __hip_bfloat16 h = __float2bfloat16(f);
    unsigned short u; __builtin_memcpy(&u, &h, 2); return u;
}

__device__ __forceinline__ float exp2g(float x) {
#if __has_builtin(__builtin_amdgcn_exp2f)
    return __builtin_amdgcn_exp2f(x);
#else
    return exp2f(x);
#endif
}

__device__ __forceinline__ float log2g(float x) {
#if __has_builtin(__builtin_amdgcn_logf)
    return __builtin_amdgcn_logf(x);
#else
    return log2f(x);
#endif
}

__global__ __launch_bounds__(512, 2) void gemm_lse_kernel(
    const float* __restrict__ z1, const float* __restrict__ z2,
    float* __restrict__ ws_sum, float* __restrict__ ws_diag)
{
    __shared__ unsigned short ldsA[2][64 * LDST];   // 2 x 33.8 KB

    const int bid  = blockIdx.x;
    const int b    = bid & 7;          // XCD-aligned batch
    const int tile = bid >> 3;
    const int mb   = tile & 7;         // 8 m-blocks of 256
    const int ns   = tile >> 3;        // 4 n-splits of 512
    const int tid  = threadIdx.x;
    const int lane = tid & 63;
    const int w    = tid >> 6;
    const int wm   = w >> 1;           // 0..3
    const int wn   = w & 1;            // 0..1
    const int col  = lane & 31;
    const int kg   = lane >> 5;

    const int m0      = mb * 256 + wm * 64;   // strip0; strip1 = +32
    const int mcol0   = m0 + col;
    const int mcol1   = m0 + 32 + col;
    const int n_start = ns * 512;

    const float* z1b = z1 + (size_t)b * SK * NN;
    const float* z2b = z2 + (size_t)b * SK * NN;

    // ---- A staging helpers ----
    float apf[4][8];
    auto load_A = [&](int t) {
        const int nbase = n_start + 64 * t;
        #pragma unroll
        for (int r = 0; r < 4; ++r) {
            const int sg = 8 * r + w;  // s-group 0..31
            const float* p = z1b + (size_t)(sg * 8) * NN + nbase + lane;
            #pragma unroll
            for (int j = 0; j < 8; ++j) apf[r][j] = p[(size_t)j * NN];
        }
    };
    auto store_A = [&](unsigned short* buf) {
        #pragma unroll
        for (int r = 0; r < 4; ++r) {
            const int sg = 8 * r + w;
            short8 pk;
            #pragma unroll
            for (int j = 0; j < 8; ++j) pk[j] = (short)f2bf(apf[r][j]);
            *(short8*)(buf + lane * LDST + sg * 8) = pk;
        }
    };

    // ---- prologue: stage tiles 0,1; build B fragments while loads land ----
    load_A(0);
    store_A(ldsA[0]);
    load_A(1);

    short8 bf0[16], bf1[16];
    #pragma unroll
    for (int ks = 0; ks < 16; ++ks) {
        short8 p0, p1;
        #pragma unroll
        for (int j = 0; j < 8; ++j) {
            const int s = ks * 16 + kg * 8 + j;
            p0[j] = (short)f2bf(z2b[s * NN + mcol0] * LOG2E);
            p1[j] = (short)f2bf(z2b[s * NN + mcol1] * LOG2E);
        }
        bf0[ks] = p0; bf1[ks] = p1;
    }

    float srun0 = 0.0f, srun1 = 0.0f;

    __syncthreads();   // buf0 visible

    for (int t = 0; t < 8; ++t) {
        const unsigned short* abase = ldsA[t & 1] + (32 * wn + col) * LDST + kg * 8;

        f32x16 acc0, acc1;
        #pragma unroll
        for (int r = 0; r < 16; ++r) { acc0[r] = -COFF; acc1[r] = -COFF; }

        #pragma unroll
        for (int ks = 0; ks < 16; ++ks) {
            short8 af = *(const short8*)(abase + ks * 16);
            acc0 = __builtin_amdgcn_mfma_f32_32x32x16_bf16(af, bf0[ks], acc0, 0, 0, 0);
            acc1 = __builtin_amdgcn_mfma_f32_32x32x16_bf16(af, bf1[ks], acc1, 0, 0, 0);
        }

        // stage tile t+1 into the other buffer (apf holds it), prefetch t+2
        if (t < 7) store_A(ldsA[(t + 1) & 1]);
        if (t < 6) load_A(t + 2);

        // diagonal capture (acc = logit' - 96; offset cancels in merge)
        const int nsub = n_start + 64 * t + 32 * wn;
        if (nsub == m0) {
            #pragma unroll
            for (int r = 0; r < 16; ++r) {
                const int row = (r & 3) + 8 * (r >> 2) + 4 * kg;
                if (row == col) ws_diag[b * NN + mcol0] = acc0[r];
            }
        }
        if (nsub == m0 + 32) {
            #pragma unroll
            for (int r = 0; r < 16; ++r) {
                const int row = (r & 3) + 8 * (r >> 2) + 4 * kg;
                if (row == col) ws_diag[b * NN + mcol1] = acc1[r];
            }
        }

        // exp2-sum, 4 independent chains per strip
        {
            float e0 = 0, e1 = 0, e2 = 0, e3 = 0;
            #pragma unroll
            for (int r = 0; r < 16; r += 4) {
                e0 += exp2g(acc0[r]);     e1 += exp2g(acc0[r + 1]);
                e2 += exp2g(acc0[r + 2]); e3 += exp2g(acc0[r + 3]);
            }
            srun0 += (e0 + e1) + (e2 + e3);
        }
        {
            float e0 = 0, e1 = 0, e2 = 0, e3 = 0;
            #pragma unroll
            for (int r = 0; r < 16; r += 4) {
                e0 += exp2g(acc1[r]);     e1 += exp2g(acc1[r + 1]);
                e2 += exp2g(acc1[r + 2]); e3 += exp2g(acc1[r + 3]);
            }
            srun1 += (e0 + e1) + (e2 + e3);
        }

        __syncthreads();   // buf[(t+1)&1] writes visible; everyone done with buf[t&1]
    }

    srun0 += __shfl_xor(srun0, 32);
    srun1 += __shfl_xor(srun1, 32);
    if (kg == 0) {
        const int slot = ns * 2 + wn;   // 8 n-partials per (b,m)
        ws_sum[(b * 8 + slot) * NN + mcol0] = srun0;
        ws_sum[(b * 8 + slot) * NN + mcol1] = srun1;
    }
}

__global__ __launch_bounds__(256) void merge_kernel(
    const float* __restrict__ ws_sum, const float* __restrict__ ws_diag,
    float* __restrict__ partial)
{
    const int gid = blockIdx.x * 256 + threadIdx.x;   // 0..16383
    const int b = gid >> 11, m = gid & (NN - 1);

    float S = 0.0f;
    #pragma unroll
    for (int slot = 0; slot < 8; ++slot)
        S += ws_sum[(b * 8 + slot) * NN + m];
    float c = log2g(S) - ws_diag[gid];   // (LSE' - diag') in log2 units

    #pragma unroll
    for (int d = 1; d < 64; d <<= 1) c += __shfl_xor(c, d);
    __shared__ float red[4];
    if ((threadIdx.x & 63) == 0) red[threadIdx.x >> 6] = c;
    __syncthreads();
    if (threadIdx.x == 0)
        partial[blockIdx.x] = red[0] + red[1] + red[2] + red[3];
}

__global__ void final_kernel(const float* __restrict__ partial, float* __restrict__ out)
{
    float v = partial[threadIdx.x];   // 64 threads
    #pragma unroll
    for (int d = 1; d < 64; d <<= 1) v += __shfl_xor(v, d);
    if (threadIdx.x == 0) out[0] = v * (LN2 / 16384.0f);
}

extern "C" void kernel_launch(void* const* d_in, const int* in_sizes, int n_in,
                              void* d_out, int out_size, void* d_ws, size_t ws_size,
                              hipStream_t stream)
{
    const float* z1 = (const float*)d_in[0];
    const float* z2 = (const float*)d_in[1];
    float* ws  = (float*)d_ws;
    float* out = (float*)d_out;

    // ws layout (floats): sum[8][8][2048] | diag[8][2048] | partial[64]
    float* ws_sum  = ws;
    float* ws_diag = ws + 131072;
    float* ws_part = ws + 147456;

    gemm_lse_kernel<<<dim3(256), dim3(512), 0, stream>>>(z1, z2, ws_sum, ws_diag);
    merge_kernel<<<dim3(64), dim3(256), 0, stream>>>(ws_sum, ws_diag, ws_part);
    final_kernel<<<dim3(1), dim3(64), 0, stream>>>(ws_part, out);
}